// Round 8
// baseline (1262.011 us; speedup 1.0000x reference)
//
#include <hip/hip_runtime.h>
#include <math.h>

#define NNODES 40000
#define NEDGES 640000
#define NPB 8             // nodes per edge-block
#define LROW 257          // padded LDS accumulator row stride (floats)

typedef __attribute__((ext_vector_type(8))) short short8_t;
typedef __attribute__((ext_vector_type(4))) float float4_t;

__device__ __forceinline__ float4 ld4(const float* p) { return *(const float4*)p; }

__device__ __forceinline__ unsigned short bf16r(float x) {
  union { float f; unsigned u; } v; v.f = x;
  unsigned u = v.u;
  u += 0x7FFFu + ((u >> 16) & 1u);   // RNE
  return (unsigned short)(u >> 16);
}

__device__ __forceinline__ void lds_fadd(float* p, float v) {
  __hip_atomic_fetch_add(p, v, __ATOMIC_RELAXED, __HIP_MEMORY_SCOPE_WORKGROUP);
}

// ---------------- Stage 1: s' = s @ W1s/sqrt(32); v' = einsum(v, W1v)/sqrt(32)
// A[n*128 + c]: c<32 -> s'[c]; c>=32 -> v'[w][i] at 32 + w*3 + i
__global__ void k1_stage1(const float* __restrict__ node_input,
                          const float* __restrict__ w1s,
                          const float* __restrict__ w1v,
                          float* __restrict__ A) {
  const float scale = 0.17677669529663687f; // 1/sqrt(32)
  int stride = gridDim.x * blockDim.x;
  for (int idx = blockIdx.x * blockDim.x + threadIdx.x; idx < NNODES * 128; idx += stride) {
    int n = idx >> 7;
    int c = idx & 127;
    const float* row = node_input + n * 128;
    float acc = 0.f;
    if (c < 32) {
      #pragma unroll
      for (int u = 0; u < 32; ++u)
        acc = fmaf(row[u], w1s[u * 32 + c], acc);
    } else {
      int cc = c - 32;
      int w = cc / 3;
      int i = cc - w * 3;
      #pragma unroll
      for (int u = 0; u < 32; ++u)
        acc = fmaf(row[32 + u * 3 + i], w1v[u * 32 + w], acc);
    }
    A[idx] = acc * scale;
  }
}

// ---------------- CSR build (round-3 proven, byte-identical) ----------------
__global__ void k_hist(const int* __restrict__ edge_dst, int* __restrict__ counts) {
  int e = blockIdx.x * blockDim.x + threadIdx.x;
  if (e < NEDGES) atomicAdd(&counts[edge_dst[e]], 1);
}

__global__ void k_scanA(const int* __restrict__ counts, int* __restrict__ bsum) {
  __shared__ int ws[4];
  int t = blockIdx.x * 256 + threadIdx.x;
  int v = (t < NNODES) ? counts[t] : 0;
  for (int d = 32; d; d >>= 1) v += __shfl_down(v, d, 64);
  if ((threadIdx.x & 63) == 0) ws[threadIdx.x >> 6] = v;
  __syncthreads();
  if (threadIdx.x == 0) bsum[blockIdx.x] = ws[0] + ws[1] + ws[2] + ws[3];
}

__global__ __launch_bounds__(256) void k_scanB(const int* __restrict__ bsum,
                                               int* __restrict__ boff,
                                               int* __restrict__ offsets) {
  __shared__ int s[256];
  int tid = threadIdx.x;
  int v = (tid < 157) ? bsum[tid] : 0;
  s[tid] = v;
  __syncthreads();
  for (int d = 1; d < 256; d <<= 1) {
    int x = (tid >= d) ? s[tid - d] : 0;
    __syncthreads();
    s[tid] += x;
    __syncthreads();
  }
  if (tid < 157) boff[tid] = s[tid] - v;
  if (tid == 0) offsets[NNODES] = NEDGES;
}

__global__ __launch_bounds__(256) void k_scanC(const int* __restrict__ counts,
                                               const int* __restrict__ boff,
                                               int* __restrict__ offsets,
                                               int* __restrict__ cursor) {
  __shared__ int s[256];
  int tid = threadIdx.x;
  int t = blockIdx.x * 256 + tid;
  int v = (t < NNODES) ? counts[t] : 0;
  s[tid] = v;
  __syncthreads();
  for (int d = 1; d < 256; d <<= 1) {
    int x = (tid >= d) ? s[tid - d] : 0;
    __syncthreads();
    s[tid] += x;
    __syncthreads();
  }
  int off = boff[blockIdx.x] + s[tid] - v;
  if (t < NNODES) { offsets[t] = off; cursor[t] = off; }
}

__global__ void k_scatter(const int* __restrict__ edge_dst,
                          int* __restrict__ cursor, int* __restrict__ slots) {
  int e = blockIdx.x * blockDim.x + threadIdx.x;
  if (e < NEDGES) {
    int d = edge_dst[e];
    int p = atomicAdd(&cursor[d], 1);
    slots[p] = e;
  }
}

// ---------------- Fused edge kernel (R7 base, one delta):
// per-thread PREFETCH of all epilogue operands at chunk start. R7 exposed the
// A-row gather latency: src came from LDS written by wave 0 in phase 1, so
// every gather waited until after the barrier and ran as 8 sequential
// load-batches per thread (VGPR=52, no MLP). Now each thread gathers
// slots->(src,dst,ea)->A for its 4 C-edges into registers up front; the
// 2-deep chain overlaps h-compute + MFMA, epilogue is pure VALU + ds_add.
// ACC row (256 floats/node): [0..31] s0 | [32..63] s1 | [64..159] v0 | [160..255] v1
__global__ __launch_bounds__(256, 4) void k_edge(
    const float* __restrict__ A,
    const int* __restrict__ edge_src,
    const int* __restrict__ edge_dst,
    const float* __restrict__ edge_attr,
    const float* __restrict__ edge_scalars,
    const float* __restrict__ fc_w1,
    const float* __restrict__ fc_w2,
    const int* __restrict__ offsets,
    const int* __restrict__ slots,
    float* __restrict__ ACC) {
  const float INV_SQRT8 = 0.35355339059327373f;
  const float H_SCALE   = 1.6791767923989418f / 8.0f; // SILU_NORM / sqrt(64)
  const float INV_SQRT3 = 0.57735026918962576f;

  __shared__ float    lacc[NPB * LROW];
  __shared__ short8_t h_frag[8 * 64];   // [(tile*2+kh)*64 + lane]: A-frag-ready h
  __shared__ short8_t w2frag[16 * 64];  // [(ctile*2+kh)*64 + lane]: B-frag-ready w2
  __shared__ float    w1t[64 * 8];      // fc_w1 transposed, pre-scaled

  int tid = threadIdx.x;
  int n0 = blockIdx.x * NPB;
  int ebase = offsets[n0];
  int eend  = offsets[n0 + NPB];

  for (int i = tid; i < NPB * LROW; i += 256) lacc[i] = 0.f;
  for (int i = tid; i < 512; i += 256) {
    int j = i >> 3, ii = i & 7;
    w1t[i] = fc_w1[ii * 64 + j] * INV_SQRT8;
  }
  // B-frag layout (R3/R7-proven): frag f=(ct*2+kh), lane l holds
  // elem j = w2[k = kh*32 + (l>>4)*8 + j][c = ct*16 + (l&15)]
  for (int fi = tid; fi < 16 * 64; fi += 256) {
    int f = fi >> 6, ll = fi & 63;
    int ct = f >> 1, kh = f & 1, mm = ll & 15, qq = ll >> 4;
    short8_t v;
    #pragma unroll
    for (int j = 0; j < 8; ++j)
      v[j] = (short)bf16r(fc_w2[(kh * 32 + qq * 8 + j) * 128 + ct * 16 + mm]);
    w2frag[fi] = v;
  }
  __syncthreads();

  int wv = tid >> 6;       // wave id 0..3
  int l  = tid & 63;
  int m  = l & 15;
  int q  = l >> 4;

  for (int k0 = ebase; k0 < eend; k0 += 64) {
    // ---- A) PREFETCH: this thread's 4 C-edges (ec = wv + 16q + 4r).
    // All loads clamped-valid so they issue unconditionally; validity only
    // predicates the final ds_adds.
    bool val4[4];
    int  e4[4], src4[4], ln4[4];
    float4 ea4[4];
    float seA[4][2], vxA[4][2], vyA[4][2], vzA[4][2];
    #pragma unroll
    for (int r = 0; r < 4; ++r) {
      int kk = k0 + (wv + 16 * q + 4 * r);
      val4[r] = kk < eend;
      e4[r] = slots[val4[r] ? kk : (eend - 1)];
    }
    #pragma unroll
    for (int r = 0; r < 4; ++r) {
      src4[r] = edge_src[e4[r]];
      ln4[r]  = edge_dst[e4[r]] - n0;
      ea4[r]  = ld4(edge_attr + (long)e4[r] * 4);
    }
    #pragma unroll
    for (int r = 0; r < 4; ++r) {
      const float* ab = A + (long)src4[r] * 128;
      #pragma unroll
      for (int uo = 0; uo < 2; ++uo) {
        int u = m + uo * 16;
        seA[r][uo] = ab[u];
        vxA[r][uo] = ab[32 + 3 * u];
        vyA[r][uo] = ab[33 + 3 * u];
        vzA[r][uo] = ab[34 + 3 * u];
      }
    }

    // ---- B) phase 1: compute h (bf16) for 64 edges (chunk-edge = lane)
    {
      int kk = k0 + l;
      bool valid = kk < eend;
      int e = slots[valid ? kk : (eend - 1)];
      float4 sA = ld4(edge_scalars + (long)e * 8);
      float4 sB = ld4(edge_scalars + (long)e * 8 + 4);
      float es8[8] = {sA.x, sA.y, sA.z, sA.w, sB.x, sB.y, sB.z, sB.w};
      unsigned short hh[16];
      #pragma unroll
      for (int jj = 0; jj < 16; ++jj) {
        int j = wv * 16 + jj;
        float4 wA = *(const float4*)&w1t[j * 8];
        float4 wB = *(const float4*)&w1t[j * 8 + 4];
        float x = es8[0]*wA.x + es8[1]*wA.y + es8[2]*wA.z + es8[3]*wA.w
                + es8[4]*wB.x + es8[5]*wB.y + es8[6]*wB.z + es8[7]*wB.w;
        float hv = valid ? (x * H_SCALE) / (1.f + __expf(-x)) : 0.f;
        hh[jj] = bf16r(hv);
      }
      // interleaved tile map (R7-proven): chunk-edge l -> tile (l&3), row (l>>2)
      int wrow = l & 3;
      int mm   = l >> 2;
      int kh   = wv >> 1;
      int qp   = (wv & 1) * 2;
      short8_t v0, v1;
      #pragma unroll
      for (int j = 0; j < 8; ++j) { v0[j] = (short)hh[j]; v1[j] = (short)hh[8 + j]; }
      h_frag[(wrow * 2 + kh) * 64 + qp * 16 + mm]       = v0;
      h_frag[(wrow * 2 + kh) * 64 + (qp + 1) * 16 + mm] = v1;
    }
    __syncthreads();

    // ---- C) MFMA (w = h @ w2): tile wv row q*4+r -> chunk-edge wv+16q+4r
    float4_t acc[8];
    {
      short8_t a0 = h_frag[(wv * 2 + 0) * 64 + l];
      short8_t a1 = h_frag[(wv * 2 + 1) * 64 + l];
      #pragma unroll
      for (int t = 0; t < 8; ++t) {
        acc[t] = (float4_t){0.f, 0.f, 0.f, 0.f};
        short8_t b0 = w2frag[(t * 2 + 0) * 64 + l];
        short8_t b1 = w2frag[(t * 2 + 1) * 64 + l];
        acc[t] = __builtin_amdgcn_mfma_f32_16x16x32_bf16(a0, b0, acc[t], 0, 0, 0);
        acc[t] = __builtin_amdgcn_mfma_f32_16x16x32_bf16(a1, b1, acc[t], 0, 0, 0);
      }
    }

    // ---- D) TP epilogue: pure VALU + ds_add on prefetched registers
    #pragma unroll
    for (int r = 0; r < 4; ++r) {
      if (val4[r]) {
        float* lrow = lacc + ln4[r] * LROW;
        float esc = ea4[r].x, ev0 = ea4[r].y, ev1 = ea4[r].z, ev2 = ea4[r].w;
        #pragma unroll
        for (int uo = 0; uo < 2; ++uo) {
          int u = m + uo * 16;
          float w0 = acc[0 + uo][r];
          float w1 = acc[2 + uo][r];
          float w2 = acc[4 + uo][r];
          float w3 = acc[6 + uo][r];
          float se = seA[r][uo];
          float vx = vxA[r][uo], vy = vyA[r][uo], vz = vzA[r][uo];
          lds_fadd(lrow + u, w0 * se * esc);
          float dv = vx * ev0 + vy * ev1 + vz * ev2;
          lds_fadd(lrow + 32 + u, w3 * dv * INV_SQRT3);
          float b1v = w1 * se;
          lds_fadd(lrow + 64 + u * 3 + 0, b1v * ev0);
          lds_fadd(lrow + 64 + u * 3 + 1, b1v * ev1);
          lds_fadd(lrow + 64 + u * 3 + 2, b1v * ev2);
          float b2v = w2 * esc;
          lds_fadd(lrow + 160 + u * 3 + 0, b2v * vx);
          lds_fadd(lrow + 160 + u * 3 + 1, b2v * vy);
          lds_fadd(lrow + 160 + u * 3 + 2, b2v * vz);
        }
      }
    }
    __syncthreads();
  }

  // write NPB node rows (coalesced); fully covers ACC (no memset needed)
  for (int i = tid; i < NPB * 256; i += 256) {
    int node = i >> 8;
    int c = i & 255;
    ACC[(long)(n0 + node) * 256 + c] = lacc[node * LROW + c];
  }
}

// ---------------- Stage 2: out_s = ns @ W2s; out_v = einsum(nv, W2v); scale 0.25/8
__global__ void k3_stage2(const float* __restrict__ ACC,
                          const float* __restrict__ w2s,
                          const float* __restrict__ w2v,
                          float* __restrict__ out) {
  const float scale = 0.03125f; // (1/sqrt(16)) / sqrt(64)
  int stride = gridDim.x * blockDim.x;
  for (int idx = blockIdx.x * blockDim.x + threadIdx.x; idx < NNODES * 128; idx += stride) {
    int n = idx >> 7;
    int c = idx & 127;
    const float* row = ACC + (long)n * 256;
    float acc = 0.f;
    if (c < 32) {
      #pragma unroll
      for (int qq = 0; qq < 64; ++qq)
        acc = fmaf(row[qq], w2s[qq * 32 + c], acc);
    } else {
      int cc = c - 32;
      int w = cc / 3;
      int i = cc - w * 3;
      #pragma unroll
      for (int qq = 0; qq < 64; ++qq)
        acc = fmaf(row[64 + qq * 3 + i], w2v[qq * 32 + w], acc);
    }
    out[idx] = acc * scale;
  }
}

extern "C" void kernel_launch(void* const* d_in, const int* in_sizes, int n_in,
                              void* d_out, int out_size, void* d_ws, size_t ws_size,
                              hipStream_t stream) {
  const float* node_input   = (const float*)d_in[0];
  const int*   edge_src     = (const int*)d_in[2];
  const int*   edge_dst     = (const int*)d_in[3];
  const float* edge_attr    = (const float*)d_in[4];
  const float* edge_scalars = (const float*)d_in[5];
  const float* w_lin1_s     = (const float*)d_in[6];
  const float* w_lin1_v     = (const float*)d_in[7];
  const float* fc_w1        = (const float*)d_in[8];
  const float* fc_w2        = (const float*)d_in[9];
  const float* w_lin2_s     = (const float*)d_in[10];
  const float* w_lin2_v     = (const float*)d_in[11];

  float* out = (float*)d_out;
  float* Abuf = out;  // stage-1 output lives in d_out; k3 overwrites it after k_edge

  // ws layout — identical footprint to the round-3 build (proven to fit)
  char* p = (char*)d_ws;
  float* ACC    = (float*)p;  p += (size_t)NNODES * 256 * sizeof(float);
  int* counts   = (int*)p;    p += (size_t)NNODES * sizeof(int);
  int* offsets  = (int*)p;    p += (size_t)(NNODES + 4) * sizeof(int);
  int* cursor   = (int*)p;    p += (size_t)NNODES * sizeof(int);
  int* slots    = (int*)p;    p += (size_t)NEDGES * sizeof(int);
  int* bsum     = (int*)p;    p += 160 * sizeof(int);
  int* boff     = (int*)p;    p += 160 * sizeof(int);

  hipMemsetAsync(counts, 0, (size_t)NNODES * sizeof(int), stream);

  k1_stage1<<<2048, 256, 0, stream>>>(node_input, w_lin1_s, w_lin1_v, Abuf);
  k_hist<<<NEDGES / 256, 256, 0, stream>>>(edge_dst, counts);
  k_scanA<<<157, 256, 0, stream>>>(counts, bsum);
  k_scanB<<<1, 256, 0, stream>>>(bsum, boff, offsets);
  k_scanC<<<157, 256, 0, stream>>>(counts, boff, offsets, cursor);
  k_scatter<<<NEDGES / 256, 256, 0, stream>>>(edge_dst, cursor, slots);
  k_edge<<<NNODES / NPB, 256, 0, stream>>>(Abuf, edge_src, edge_dst, edge_attr,
                                           edge_scalars, fc_w1, fc_w2,
                                           offsets, slots, ACC);
  k3_stage2<<<2048, 256, 0, stream>>>(ACC, w_lin2_s, w_lin2_v, out);
}